// Round 3
// baseline (519.010 us; speedup 1.0000x reference)
//
#include <hip/hip_runtime.h>
#include <hip/hip_bf16.h>

#define B_    32
#define CIN   128
#define COUT  128
#define NN    128
#define PPAD  130   // padded p dimension (1 zero col each side)

typedef __attribute__((ext_vector_type(8))) short short8;
typedef __attribute__((ext_vector_type(4))) float float4v;

static __device__ inline unsigned short f2bf(float f) {
    union { float f; unsigned u; } v; v.f = f;
    unsigned u = v.u;
    unsigned r = u + 0x7FFFu + ((u >> 16) & 1u);   // RNE
    return (unsigned short)(r >> 16);
}

// ---------------------------------------------------------------------------
// x [B][C][N][N] f32  ->  xT [B][N(row)][PPAD][C] bf16, zero cols pp=0,129
// ---------------------------------------------------------------------------
__global__ __launch_bounds__(256) void xpose_kernel(const float* __restrict__ x,
                                                    unsigned short* __restrict__ xT) {
    int b = blockIdx.x >> 7;
    int i = blockIdx.x & 127;
    __shared__ unsigned short tile[CIN * PPAD];   // [c][p], row stride 130
    int tid = threadIdx.x;
    const float* src = x + ((size_t)(b * CIN) * NN + i) * NN;  // x[b][0][i][0]
    #pragma unroll
    for (int e = 0; e < 64; ++e) {
        int idx = e * 256 + tid;
        int c = idx >> 7;
        int p = idx & 127;
        tile[c * PPAD + p] = f2bf(src[(size_t)c * (NN * NN) + p]);
    }
    __syncthreads();
    unsigned short* dst = xT + (size_t)(b * NN + i) * PPAD * CIN;
    #pragma unroll
    for (int e = 0; e < 32; ++e) {
        int pi = e * 256 + tid;          // 0..8191
        int c2 = (pi & 63) * 2;
        int p  = pi >> 6;
        ushort2 v;
        v.x = tile[c2 * PPAD + p];
        v.y = tile[(c2 + 1) * PPAD + p];
        *(ushort2*)(dst + (size_t)(p + 1) * CIN + c2) = v;
    }
    if (tid < 128) {
        dst[tid] = 0;
        dst[(size_t)129 * CIN + tid] = 0;
    }
}

// ---------------------------------------------------------------------------
// kernel [O][C][3][3] f32 -> kT [kd][O][C] bf16   (kd = k*3+d)
// ---------------------------------------------------------------------------
__global__ __launch_bounds__(256) void ktrans_kernel(const float* __restrict__ kern,
                                                     unsigned short* __restrict__ kT) {
    int idx = blockIdx.x * 256 + threadIdx.x;     // 0..147455
    if (idx >= COUT * CIN * 9) return;
    int c  = idx & 127;
    int t  = idx >> 7;
    int o  = t & 127;
    int kd = t >> 7;                              // 0..8
    int k = kd / 3, d = kd % 3;
    kT[idx] = f2bf(kern[(((size_t)o * CIN + c) * 3 + k) * 3 + d]);
}

// ---------------------------------------------------------------------------
// main v3: one block per (b, row-pair). 512 threads, 8 waves, 2 blocks/CU.
// x staged per 64-channel half (66.5 KB LDS, XOR-swizzled); kT from L2/L1.
// wave tile: 64 o x 64 pixels; acc carried across both channel halves.
// ---------------------------------------------------------------------------
#define CH     64                      // channels per staging phase
#define NSLOT3 (4 * PPAD * 8)          // 16B slots per phase = 4160
#define SLOTS_PER_ROW3 (PPAD * 8)      // 1040

__global__ __launch_bounds__(512, 4) void conv_mfma3_kernel(const unsigned short* __restrict__ xT,
                                                            const unsigned short* __restrict__ kT,
                                                            float* __restrict__ out) {
    __shared__ unsigned short xs[4 * PPAD * CH];   // 66,560 B -> 2 blocks/CU

    // bijective XCD swizzle: 2048 blocks, 8 XCDs, 256-block contiguous slabs
    int wg = blockIdx.x;
    int lb = (wg & 7) * 256 + (wg >> 3);
    int b  = lb >> 6;
    int i0 = (lb & 63) * 2;

    int tid  = threadIdx.x;
    int lane = tid & 63;
    int wave = tid >> 6;
    int wr = wave >> 2;            // o half (0/1)
    int wc = wave & 3;             // (row, p-half)
    int ri = wc >> 1;              // which output row of the pair
    int pb = (wc & 1) * 64;        // p base
    int ob = wr * 64;              // o base
    int l15 = lane & 15;
    int lg  = lane >> 4;           // 0..3

    float4v acc[4][4];
    #pragma unroll
    for (int m = 0; m < 4; ++m)
        #pragma unroll
        for (int n = 0; n < 4; ++n)
            acc[m][n] = (float4v)(0.0f);

    const unsigned short* xb = xT + (size_t)b * NN * PPAD * CIN;

    for (int ch = 0; ch < 2; ++ch) {
        // ---- stage 64-channel half of rows i0-1 .. i0+2 ----
        // position slot j holds content c-slot = j ^ (pp&7)
        #pragma unroll
        for (int s = 0; s < 9; ++s) {
            int W = s * 512 + tid;
            if (W < NSLOT3) {
                int r   = W / SLOTS_PER_ROW3;      // 0..3
                int rem = W - r * SLOTS_PER_ROW3;
                int pp  = rem >> 3;                // 0..129
                int j   = rem & 7;                 // slot position
                int csl = j ^ (pp & 7);            // content c-slot
                int grow = i0 - 1 + r;             // -1..128
                short8 v;
                if (grow >= 0 && grow < NN) {
                    v = *(const short8*)(xb + ((size_t)grow * PPAD + pp) * CIN + ch * CH + csl * 8);
                } else {
                    v = (short8)(0);
                }
                *(short8*)(&xs[(size_t)W * 8]) = v;
            }
        }
        __syncthreads();

        #pragma unroll
        for (int kd = 0; kd < 9; ++kd) {
            const int k = kd / 3, d = kd % 3;
            const int lrow = ri + k;                    // LDS row 0..3
            const unsigned short* krow = kT + (size_t)kd * COUT * CIN;
            #pragma unroll
            for (int cc = 0; cc < 2; ++cc) {
                short8 a[4], bt[4];
                #pragma unroll
                for (int m = 0; m < 4; ++m) {
                    int o = ob + m * 16 + l15;
                    a[m] = *(const short8*)(krow + (size_t)o * CIN + ch * CH + cc * 32 + lg * 8);
                }
                #pragma unroll
                for (int n = 0; n < 4; ++n) {
                    int pp = pb + n * 16 + l15 + d;     // 0..129
                    int slot = (cc * 4 + lg) ^ (pp & 7);
                    bt[n] = *(const short8*)(&xs[((size_t)(lrow * PPAD + pp)) * CH + slot * 8]);
                }
                #pragma unroll
                for (int m = 0; m < 4; ++m)
                    #pragma unroll
                    for (int n = 0; n < 4; ++n)
                        acc[m][n] = __builtin_amdgcn_mfma_f32_16x16x32_bf16(a[m], bt[n], acc[m][n], 0, 0, 0);
            }
        }
        __syncthreads();
    }

    // store: D col = lane&15 -> p, row = (lane>>4)*4 + r -> o
    float* op = out + ((size_t)(b * COUT) * NN + (i0 + ri)) * NN;
    #pragma unroll
    for (int m = 0; m < 4; ++m) {
        #pragma unroll
        for (int n = 0; n < 4; ++n) {
            int p = pb + n * 16 + l15;
            #pragma unroll
            for (int r = 0; r < 4; ++r) {
                int o = ob + m * 16 + lg * 4 + r;
                op[(size_t)o * (NN * NN) + p] = acc[m][n][r];
            }
        }
    }
}

// ---------------------------------------------------------------------------
// fallback: naive direct conv (only if workspace too small)
// ---------------------------------------------------------------------------
__global__ __launch_bounds__(256) void conv_naive_kernel(const float* __restrict__ x,
                                                         const float* __restrict__ kern,
                                                         float* __restrict__ out) {
    size_t idx = (size_t)blockIdx.x * 256 + threadIdx.x;
    int p = idx & 127;
    size_t t = idx >> 7;
    int i = t & 127; t >>= 7;
    int o = t & 127;
    int b = (int)(t >> 7);
    float s = 0.f;
    for (int c = 0; c < CIN; ++c) {
        #pragma unroll
        for (int k = 0; k < 3; ++k) {
            int r = i + k - 1;
            if (r < 0 || r >= NN) continue;
            #pragma unroll
            for (int d = 0; d < 3; ++d) {
                int q = p + d - 1;
                if (q < 0 || q >= NN) continue;
                s += kern[(((size_t)o * CIN + c) * 3 + k) * 3 + d]
                   * x[(((size_t)b * CIN + c) * NN + r) * NN + q];
            }
        }
    }
    out[idx] = s;
}

extern "C" void kernel_launch(void* const* d_in, const int* in_sizes, int n_in,
                              void* d_out, int out_size, void* d_ws, size_t ws_size,
                              hipStream_t stream) {
    const float* x    = (const float*)d_in[0];
    const float* kern = (const float*)d_in[1];
    float* out = (float*)d_out;

    const size_t xT_bytes = (size_t)B_ * NN * PPAD * CIN * 2;   // 136,314,880
    const size_t kT_bytes = (size_t)9 * COUT * CIN * 2;         //     294,912

    if (ws_size >= xT_bytes + kT_bytes) {
        unsigned short* xT = (unsigned short*)d_ws;
        unsigned short* kT = (unsigned short*)((char*)d_ws + xT_bytes);
        hipLaunchKernelGGL(xpose_kernel, dim3(B_ * NN), dim3(256), 0, stream, x, xT);
        hipLaunchKernelGGL(ktrans_kernel, dim3(576), dim3(256), 0, stream, kern, kT);
        hipLaunchKernelGGL(conv_mfma3_kernel, dim3(B_ * NN / 2), dim3(512), 0, stream, xT, kT, out);
    } else {
        hipLaunchKernelGGL(conv_naive_kernel, dim3(67108864 / 256), dim3(256), 0, stream,
                           x, kern, out);
    }
}